// Round 1
// baseline (22.744 us; speedup 1.0000x reference)
//
#include <hip/hip_runtime.h>
#include <hip/hip_bf16.h>

// Segment-mean over sorted indexes.
// hidden: [B=8, S=2048, D=768] f32; ori_indexes: [B, S] sorted int (values < T=1024)
// out:    [B, T=1024, D] f32 = segment_sum(hidden, idx) / clip(count, 1)
//
// One block per (b, t). Indexes are sorted, so token t's rows are the
// contiguous range [lower_bound(t), lower_bound(t+1)). Two binary searches
// over the L1-resident 8KB index row, then a coalesced float4 sum.
// Every (b,t,d) is written exactly once -> no atomics, no pre-zeroing,
// fully deterministic.

#define SGA_B 8
#define SGA_S 2048
#define SGA_D 768
#define SGA_T 1024

__global__ __launch_bounds__(SGA_D / 4) void sga_segmean_kernel(
    const float* __restrict__ hidden,
    const int* __restrict__ idx,
    float* __restrict__ out) {
    const int t = blockIdx.x;   // 0..T-1
    const int b = blockIdx.y;   // 0..B-1
    const int tid = threadIdx.x;  // 0..191 (D/4 float4 lanes)

    const int* ib = idx + b * SGA_S;

    // lower_bound(t)
    int lo = 0, hi = SGA_S;
    while (lo < hi) {
        int m = (lo + hi) >> 1;
        if (ib[m] < t) lo = m + 1; else hi = m;
    }
    const int start = lo;
    // lower_bound(t+1), continuing from start
    hi = SGA_S;
    while (lo < hi) {
        int m = (lo + hi) >> 1;
        if (ib[m] < t + 1) lo = m + 1; else hi = m;
    }
    const int end = lo;

    const int cnt = end - start;
    const float inv = (cnt > 0) ? (1.0f / (float)cnt) : 0.0f;

    const float4* __restrict__ hrow =
        reinterpret_cast<const float4*>(hidden) + (size_t)b * SGA_S * (SGA_D / 4);

    float4 acc = make_float4(0.f, 0.f, 0.f, 0.f);
    for (int s = start; s < end; ++s) {
        float4 v = hrow[(size_t)s * (SGA_D / 4) + tid];
        acc.x += v.x; acc.y += v.y; acc.z += v.z; acc.w += v.w;
    }
    acc.x *= inv; acc.y *= inv; acc.z *= inv; acc.w *= inv;

    float4* __restrict__ orow =
        reinterpret_cast<float4*>(out) + ((size_t)b * SGA_T + t) * (SGA_D / 4);
    orow[tid] = acc;
}

extern "C" void kernel_launch(void* const* d_in, const int* in_sizes, int n_in,
                              void* d_out, int out_size, void* d_ws, size_t ws_size,
                              hipStream_t stream) {
    const float* hidden = (const float*)d_in[0];
    const int* idx = (const int*)d_in[1];
    float* out = (float*)d_out;

    dim3 grid(SGA_T, SGA_B, 1);
    dim3 block(SGA_D / 4, 1, 1);  // 192 threads = 3 waves
    sga_segmean_kernel<<<grid, block, 0, stream>>>(hidden, idx, out);
}